// Round 14
// baseline (163.517 us; speedup 1.0000x reference)
//
#include <hip/hip_runtime.h>
#include <hip/hip_fp16.h>

// Problem constants (match reference)
constexpr int N_  = 100000;   // nodes
constexpr int E_  = 1600000;  // edges
constexpr int B_  = 2048;     // pairs
constexpr int NT_ = 2 * B_;   // 4096 target nodes (users+items) read by MLP

constexpr int NPB_SHIFT = 8;                    // 256 nodes per bucket
constexpr int NPB = 1 << NPB_SHIFT;
constexpr int KB_ = (N_ + NPB - 1) / NPB;       // 391 buckets
constexpr int CAP_ = 4608;                      // per-bucket capacity (mean 4096, +8 sigma)
constexpr int PCHUNK = 6250;                    // edges per partition block
constexpr int NPBLK = (E_ + PCHUNK - 1) / PCHUNK; // 256 blocks
constexpr int NTB_ = NT_ / NPB;                 // 16 needed-set blocks (buckets 0..15)
constexpr int HSTR = 21;                        // hist stride (odd -> no bank conflict)
constexpr int PPB = 8;                          // MLP pairs per block

// ==== partition+ : edge partition, plus init work (cls/flag, w1t) in extra blocks ===
// Blocks [0,NPBLK): edge partition. [NPBLK,NPBLK+391): cls+flag. [+391,+519): w1t.
// pack word = src(17) | etype(3)<<17 | dloc(8)<<20
__global__ __launch_bounds__(256) void partition_kernel(
    const float* __restrict__ x, const float* __restrict__ w1,
    const int* __restrict__ src, const int* __restrict__ dst,
    const int* __restrict__ etype, int* __restrict__ bcur, int* __restrict__ ebuf,
    unsigned char* __restrict__ cls, int* __restrict__ flag, float* __restrict__ w1t)
{
    const int b = blockIdx.x, t = threadIdx.x;
    if (b >= NPBLK) {
        const int bb = b - NPBLK;
        if (bb < 391) {                        // cls + flag init
            const int n = bb * 256 + t;
            if (n < N_) {
                const float4 v = *(const float4*)(x + n * 4);
                cls[n] = v.y > 0.5f ? 1 : (v.z > 0.5f ? 2 : (v.w > 0.5f ? 3 : 0));
                flag[n] = 0;
            }
        } else {                               // w1 transpose (128 blocks)
            const int idx = (bb - 391) * 256 + t;   // < 32768
            const int j = idx >> 8, k = idx & 255;
            w1t[k * 128 + j] = w1[idx];
        }
        return;
    }
    __shared__ int hist[KB_];
    __shared__ int gbase[KB_];
    __shared__ int lcur[KB_];
    for (int i = t; i < KB_; i += 256) { hist[i] = 0; lcur[i] = 0; }
    __syncthreads();
    const int e0 = b * PCHUNK;
    const int e1 = min(e0 + PCHUNK, E_);
    for (int i = e0 + t; i < e1; i += 256) atomicAdd(&hist[dst[i] >> NPB_SHIFT], 1);
    __syncthreads();
    for (int i = t; i < KB_; i += 256) if (hist[i]) gbase[i] = atomicAdd(&bcur[i], hist[i]);
    __syncthreads();
    for (int i = e0 + t; i < e1; i += 256) {
        const int d = dst[i];
        const int bk = d >> NPB_SHIFT;
        const int lp = atomicAdd(&lcur[bk], 1);
        ebuf[(size_t)bk * CAP_ + gbase[bk] + lp] = src[i] | (etype[i] << 17) | ((d & (NPB - 1)) << 20);
    }
}

// == fused per-bucket: bucket-scan -> hist -> node-scan -> rowptr -> scatter -> L0 ==
// Blocks [0,KB_): CSR + layer 0 for a 256-node bucket. Blocks [KB_,KB_+NTB_):
// needed-set for pruned layer 2 (LDS-buffered appends, 1 global atomic per block).
__global__ __launch_bounds__(512) void bfinish_kernel(
    const int* __restrict__ bcur, const int* __restrict__ ebuf,
    const unsigned char* __restrict__ cls,
    const float* __restrict__ comp0, const float* __restrict__ V0,
    const float* __restrict__ loop0, const float* __restrict__ bias0,
    int* __restrict__ rowptr, int* __restrict__ pack,
    float* __restrict__ cs, __half* __restrict__ hout,
    int* __restrict__ flag, int* __restrict__ cnt_g, int* __restrict__ nlist)
{
    __shared__ int cnt[NPB];                 // scatter cursors
    __shared__ int sh[512];                  // scan workspace (bucket + node scans)
    __shared__ unsigned int hist[NPB * HSTR];// (rel x cls) histogram per node
    __shared__ float sLoop[128], sV0[256], sBias[32], sCmp[10];
    __shared__ int lcnt, gbase_s;
    const int b = blockIdx.x, t = threadIdx.x;
    if (b >= KB_) {
        // ---- needed-set: targets + dedup'd srcs of edges into [0,NT_) ----
        const int tb = b - KB_;              // 0..NTB_-1
        const int s0 = tb * CAP_;
        const int s1 = s0 + bcur[tb];
        const int nbase = tb << NPB_SHIFT;
        int* lbuf = (int*)hist;              // 5376 ints >= 256 + 4608 worst case
        if (t == 0) lcnt = NPB;
        if (t < NPB) lbuf[t] = nbase + t;
        __syncthreads();
        for (int i = s0 + t; i < s1; i += 512) {
            const int s = ebuf[i] & 0x1FFFF;
            if (s >= NT_ && atomicExch(&flag[s], 1) == 0)
                lbuf[atomicAdd(&lcnt, 1)] = s;
        }
        __syncthreads();
        if (t == 0) gbase_s = atomicAdd(cnt_g, lcnt);
        __syncthreads();
        for (int j = t; j < lcnt; j += 512) nlist[gbase_s + j] = lbuf[j];
        return;
    }
    for (int i = t; i < NPB * HSTR; i += 512) hist[i] = 0u;
    if (t < 128) sLoop[t] = loop0[t];
    if (t < 256) sV0[t]   = V0[t];
    if (t < 32)  sBias[t] = bias0[t];
    if (t < 10)  sCmp[t]  = comp0[t];
    // ---- folded bucket scan: exclusive prefix of bcur over KB_ (<512) buckets ----
    sh[t] = (t < KB_) ? bcur[t] : 0;
    __syncthreads();
#pragma unroll
    for (int off = 1; off < 512; off <<= 1) {
        const int u = (t >= off) ? sh[t - off] : 0;
        __syncthreads();
        sh[t] += u;
        __syncthreads();
    }
    const int myCnt = bcur[b];
    const int db = sh[b] - myCnt;            // dense base for this bucket
    const int s0 = b * CAP_;
    const int s1 = s0 + myCnt;
    __syncthreads();                         // sh free for reuse
    for (int i = s0 + t; i < s1; i += 512) {
        const int p = ebuf[i];
        const int et_c = ((p >> 17) & 7) * 4 + cls[p & 0x1FFFF];
        atomicAdd(&hist[(p >> 20) * HSTR + et_c], 1u);
    }
    __syncthreads();
    int v = 0;                               // degree = sum of node's 20 hist entries
    if (t < NPB) {
#pragma unroll
        for (int j = 0; j < 20; ++j) v += (int)hist[t * HSTR + j];
    }
    sh[t] = (t < NPB) ? v : 0;
    __syncthreads();
#pragma unroll
    for (int off = 1; off < NPB; off <<= 1) {
        const int u = (t >= off) ? sh[t - off] : 0;
        __syncthreads();
        sh[t] += u;
        __syncthreads();
    }
    const int node = (b << NPB_SHIFT) + t;
    if (t < NPB) {
        const int rp = db + sh[t] - v;       // dense exclusive prefix + bucket base
        if (node < N_) rowptr[node] = rp;
        cnt[t] = rp;                         // scatter cursor
    }
    if (b == 0 && t == 0) rowptr[N_] = E_;
    __syncthreads();
    for (int i = s0 + t; i < s1; i += 512) {
        const int p = ebuf[i];
        const int pos = atomicAdd(&cnt[p >> 20], 1);
        pack[pos] = p & 0xFFFFF;             // src | etype<<17
    }
    // ---- layer 0 output for this bucket's nodes (hist is stable) ----
    if (t < NPB && node < N_) {
        float A0[4], A1[4];
#pragma unroll
        for (int j = 0; j < 4; ++j) {
            float a0 = 0.f, a1 = 0.f;
#pragma unroll
            for (int r = 0; r < 5; ++r) {
                const float c = (float)hist[t * HSTR + r * 4 + j];
                a0 += c * sCmp[r * 2];
                a1 += c * sCmp[r * 2 + 1];
            }
            A0[j] = a0; A1[j] = a1;
        }
        const int myc = cls[node];
        __half hrow[32];
        const bool wcs = node < NT_;
#pragma unroll 8
        for (int d = 0; d < 32; ++d) {
            float o = sBias[d] + sLoop[myc * 32 + d];
#pragma unroll
            for (int j = 0; j < 4; ++j)
                o += A0[j] * sV0[j * 32 + d] + A1[j] * sV0[128 + j * 32 + d];
            const float r = tanhf(o);
            hrow[d] = __float2half(r);
            if (wcs) cs[node * 128 + d] = r;
        }
        uint4* dst4 = (uint4*)(hout + (size_t)node * 32);
        const uint4* src4 = (const uint4*)hrow;
        dst4[0] = src4[0]; dst4[1] = src4[1]; dst4[2] = src4[2]; dst4[3] = src4[3];
    }
}

// ======================= shared gather body (K = 32) =======================
// 4 lanes per edge; packed fp16 edge accumulation; packed fp16 cross-slot
// reduce; matvec with float4 LDS broadcast reads + coalesced weight reads.
__device__ __forceinline__ void acc_chunk(
    const uint4& v, int pq, bool ok, const __half2* __restrict__ cmp2,
    __half2* h0, __half2* h1)
{
    const int tt = (pq >> 17) & 7;
    const __half2 z = __float2half2_rn(0.f);
    const __half2 c0 = ok ? cmp2[tt * 2]     : z;
    const __half2 c1 = ok ? cmp2[tt * 2 + 1] : z;
    const __half2* hp = (const __half2*)&v;
#pragma unroll
    for (int k = 0; k < 4; ++k) {
        h0[k] = __hfma2(c0, hp[k], h0[k]);
        h1[k] = __hfma2(c1, hp[k], h1[k]);
    }
}

__device__ __forceinline__ float gather_body(
    int n, int lane, int g,
    const __half* __restrict__ hin, const int* __restrict__ rowptr,
    const int* __restrict__ pack, const __half2* __restrict__ cmp2,
    const float* __restrict__ V, const float* __restrict__ loopW,
    const float* __restrict__ bias, float (*hs)[96])
{
    hs[g][lane] = __half2float(hin[n * 32 + lane]);
    const int beg = rowptr[n], end = rowptr[n + 1];
    const int sg = lane >> 2;       // edge slot 0..7
    const int c  = lane & 3;        // dim chunk: dims 8c..8c+7
    const int i0 = beg + sg, i1 = i0 + 8, i2 = i0 + 16, i3 = i0 + 24;
    // 4 independent pack loads
    const int p0 = pack[i0 < end ? i0 : beg];
    const int p1 = pack[i1 < end ? i1 : beg];
    const int p2 = pack[i2 < end ? i2 : beg];
    const int p3 = pack[i3 < end ? i3 : beg];
    // 4 h loads, each dependent only on its own pack word
    const uint4 v0 = *(const uint4*)(hin + (size_t)(p0 & 0x1FFFF) * 32 + c * 8);
    const uint4 v1 = *(const uint4*)(hin + (size_t)(p1 & 0x1FFFF) * 32 + c * 8);
    const uint4 v2 = *(const uint4*)(hin + (size_t)(p2 & 0x1FFFF) * 32 + c * 8);
    const uint4 v3 = *(const uint4*)(hin + (size_t)(p3 & 0x1FFFF) * 32 + c * 8);
    __half2 h0[4], h1[4];
    const __half2 z = __float2half2_rn(0.f);
#pragma unroll
    for (int k = 0; k < 4; ++k) { h0[k] = z; h1[k] = z; }
    acc_chunk(v0, p0, i0 < end, cmp2, h0, h1);
    acc_chunk(v1, p1, i1 < end, cmp2, h0, h1);
    acc_chunk(v2, p2, i2 < end, cmp2, h0, h1);
    acc_chunk(v3, p3, i3 < end, cmp2, h0, h1);
    // rare tail: deg > 32
    for (int e0 = beg + 32; e0 < end; e0 += 8) {
        const int e = e0 + sg;
        const bool ok = e < end;
        const int p = pack[ok ? e : beg];
        const uint4 u = *(const uint4*)(hin + (size_t)(p & 0x1FFFF) * 32 + c * 8);
        acc_chunk(u, p, ok, cmp2, h0, h1);
    }
    // packed fp16 cross-slot reduce (3 rounds over 8 half2 words)
#pragma unroll
    for (int m = 4; m <= 16; m <<= 1) {
#pragma unroll
        for (int k = 0; k < 4; ++k) {
            const int r0 = __shfl_xor(__builtin_bit_cast(int, h0[k]), m, 32);
            const int r1 = __shfl_xor(__builtin_bit_cast(int, h1[k]), m, 32);
            h0[k] = __hadd2(h0[k], __builtin_bit_cast(__half2, r0));
            h1[k] = __hadd2(h1[k], __builtin_bit_cast(__half2, r1));
        }
    }
    if (lane < 4) {
#pragma unroll
        for (int k = 0; k < 4; ++k) {
            const float2 f0 = __half22float2(h0[k]);
            const float2 f1 = __half22float2(h1[k]);
            hs[g][32 + c * 8 + 2 * k]     = f0.x;
            hs[g][32 + c * 8 + 2 * k + 1] = f0.y;
            hs[g][64 + c * 8 + 2 * k]     = f1.x;
            hs[g][64 + c * 8 + 2 * k + 1] = f1.y;
        }
    }
    __builtin_amdgcn_wave_barrier();   // 32-lane group is within one wave64
    // matvec: float4 LDS broadcast reads, weight reads coalesced across lanes
    float o = bias[lane];
#pragma unroll
    for (int k0 = 0; k0 < 32; k0 += 4) {
        const float4 s  = *(const float4*)&hs[g][k0];
        const float4 sa = *(const float4*)&hs[g][32 + k0];
        const float4 sb = *(const float4*)&hs[g][64 + k0];
        o += s.x  * loopW[(k0 + 0) * 32 + lane] + s.y  * loopW[(k0 + 1) * 32 + lane]
           + s.z  * loopW[(k0 + 2) * 32 + lane] + s.w  * loopW[(k0 + 3) * 32 + lane]
           + sa.x * V[(k0 + 0) * 32 + lane]     + sa.y * V[(k0 + 1) * 32 + lane]
           + sa.z * V[(k0 + 2) * 32 + lane]     + sa.w * V[(k0 + 3) * 32 + lane]
           + sb.x * V[1024 + (k0 + 0) * 32 + lane] + sb.y * V[1024 + (k0 + 1) * 32 + lane]
           + sb.z * V[1024 + (k0 + 2) * 32 + lane] + sb.w * V[1024 + (k0 + 3) * 32 + lane];
    }
    return tanhf(o);
}

// Full-sweep gather (layer 1): n = blockIdx*8+g, grid exact
__global__ __launch_bounds__(256) void gather_kernel(
    const __half* __restrict__ hin, const int* __restrict__ rowptr,
    const int* __restrict__ pack, const float* __restrict__ comp,
    const float* __restrict__ V, const float* __restrict__ loopW,
    const float* __restrict__ bias,
    float* __restrict__ cs, __half* __restrict__ hout, int out_off)
{
    __shared__ __align__(16) float hs[8][96];
    __shared__ __half2 cmp2[10];
    const int t = threadIdx.x, lane = t & 31, g = t >> 5;
    if (lane < 10) cmp2[lane] = __float2half2_rn(comp[lane]);  // per-wave benign race
    __builtin_amdgcn_wave_barrier();
    const int n = blockIdx.x * 8 + g;
    const float r = gather_body(n, lane, g, hin, rowptr, pack, cmp2, V, loopW, bias, hs);
    if (n < NT_) cs[n * 128 + out_off + lane] = r;
    hout[n * 32 + lane] = __float2half(r);
}

// Pruned gather over compacted node list (barrier-free -> early exit legal)
__global__ __launch_bounds__(256) void gatherL_kernel(
    const __half* __restrict__ hin, const int* __restrict__ rowptr,
    const int* __restrict__ pack, const float* __restrict__ comp,
    const float* __restrict__ V, const float* __restrict__ loopW,
    const float* __restrict__ bias,
    const int* __restrict__ nlist, const int* __restrict__ cnt,
    float* __restrict__ cs, __half* __restrict__ hout, int out_off)
{
    __shared__ __align__(16) float hs[8][96];
    __shared__ __half2 cmp2[10];
    const int t = threadIdx.x, lane = t & 31, g = t >> 5;
    if (lane < 10) cmp2[lane] = __float2half2_rn(comp[lane]);
    __builtin_amdgcn_wave_barrier();
    const int idx = blockIdx.x * 8 + g;
    if (idx >= *cnt) return;                 // no block barriers below: safe
    const int n = nlist[idx];
    const float r = gather_body(n, lane, g, hin, rowptr, pack, cmp2, V, loopW, bias, hs);
    if (n < NT_) cs[n * 128 + out_off + lane] = r;
    hout[n * 32 + lane] = __float2half(r);
}

// ====== MLP head, 8 pairs/block: fused layer-3 gathers + block-shared w1t ======
// Phase 1: 8 wave-groups x 2 rounds gather 16 target rows (layer 3) into feat,
// lanes also load cs[0..95]. Phase 2: 256 threads each compute 4 hidden units.
__global__ __launch_bounds__(256) void mlp_kernel(
    const __half* __restrict__ hin, const int* __restrict__ rowptr,
    const int* __restrict__ pack, const float* __restrict__ comp,
    const float* __restrict__ V, const float* __restrict__ loopW,
    const float* __restrict__ bias,
    const float* __restrict__ cs, const float* __restrict__ w1t,
    const float* __restrict__ b1, const float* __restrict__ w2,
    const float* __restrict__ b2, float* __restrict__ out)
{
    __shared__ __align__(16) float feat[PPB][256];
    __shared__ __align__(16) float hs[8][96];
    __shared__ __half2 cmp2[10];
    __shared__ float red[PPB][2];
    const int t = threadIdx.x, lane = t & 31, g = t >> 5;
    const int p0 = blockIdx.x * PPB;
    if (lane < 10) cmp2[lane] = __float2half2_rn(comp[lane]);  // per-wave benign race
    __builtin_amdgcn_wave_barrier();
#pragma unroll
    for (int r = 0; r < 2; ++r) {
        const int idx = r * 8 + g;           // 0..15
        const int pp = idx >> 1, who = idx & 1;
        const int n = who ? (B_ + p0 + pp) : (p0 + pp);
        const float rv = gather_body(n, lane, g, hin, rowptr, pack, cmp2, V, loopW, bias, hs);
        feat[pp][who * 128 + 96 + lane] = rv;
        const int base = n * 128;
        feat[pp][who * 128 + lane]      = cs[base + lane];
        feat[pp][who * 128 + 32 + lane] = cs[base + 32 + lane];
        feat[pp][who * 128 + 64 + lane] = cs[base + 64 + lane];
    }
    __syncthreads();
    const int j = t & 127;                   // hidden unit
    const int half = t >> 7;                 // 0 or 1
    const int wInHalf = (t >> 6) & 1;        // wave within half
    const float bj = b1[j], w2j = w2[j];
    float acc[4];
#pragma unroll
    for (int i = 0; i < 4; ++i) acc[i] = bj;
#pragma unroll 4
    for (int k0 = 0; k0 < 256; k0 += 4) {
        const float wa = w1t[(k0 + 0) * 128 + j];
        const float wb = w1t[(k0 + 1) * 128 + j];
        const float wc = w1t[(k0 + 2) * 128 + j];
        const float wd = w1t[(k0 + 3) * 128 + j];
#pragma unroll
        for (int i = 0; i < 4; ++i) {
            const float4 f = *(const float4*)&feat[half * 4 + i][k0];
            acc[i] += f.x * wa + f.y * wb + f.z * wc + f.w * wd;
        }
    }
#pragma unroll
    for (int i = 0; i < 4; ++i) {
        float v = w2j * (acc[i] > 0.f ? acc[i] : 0.f);
#pragma unroll
        for (int off = 32; off > 0; off >>= 1) v += __shfl_down(v, off, 64);
        if ((t & 63) == 0) red[half * 4 + i][wInHalf] = v;
    }
    __syncthreads();
    if (t < PPB) out[p0 + t] = red[t][0] + red[t][1] + b2[0];
}

extern "C" void kernel_launch(void* const* d_in, const int* in_sizes, int n_in,
                              void* d_out, int out_size, void* d_ws, size_t ws_size,
                              hipStream_t stream) {
    const float* x      = (const float*)d_in[0];
    const int*   src    = (const int*)d_in[1];
    const int*   dst    = (const int*)d_in[2];
    const int*   etype  = (const int*)d_in[3];
    const float* V0     = (const float*)d_in[4];
    const float* comp0  = (const float*)d_in[5];
    const float* loop0  = (const float*)d_in[6];
    const float* bias0  = (const float*)d_in[7];
    const float* Vs     = (const float*)d_in[8];    // [3,2,32,32]
    const float* comps  = (const float*)d_in[9];    // [3,5,2]
    const float* loops  = (const float*)d_in[10];   // [3,32,32]
    const float* biases = (const float*)d_in[11];   // [3,32]
    const float* w1     = (const float*)d_in[12];   // [128,256]
    const float* b1     = (const float*)d_in[13];
    const float* w2     = (const float*)d_in[14];   // [1,128]
    const float* b2     = (const float*)d_in[15];
    float* out = (float*)d_out;

    // Workspace layout
    float* ws   = (float*)d_ws;
    float* cs   = ws;                          // NT_*128 floats (target rows only)
    float* w1t  = cs + (size_t)NT_ * 128;      // 256*128 floats
    __half* hA  = (__half*)(w1t + 256 * 128);  // N*32 halves
    __half* hB  = hA + (size_t)N_ * 32;        // N*32 halves
    int* ebuf   = (int*)(hB + (size_t)N_ * 32);   // KB_*CAP_
    int* pack   = ebuf + (size_t)KB_ * CAP_;   // E
    int* rowptr = pack + E_;                   // N+1
    int* flag   = rowptr + N_ + 1;             // N
    int* nlist  = flag + N_;                   // N
    int* bcur   = nlist + N_;                  // KB_
    int* cnt    = bcur + KB_;                  // 1 (contiguous with bcur for memset)
    unsigned char* cls = (unsigned char*)(cnt + 1);  // N bytes

    const int gathBlocks = N_ / 8;             // 12500 (exact)

    // 1. zero bcur + cnt (single contiguous memset)
    hipMemsetAsync(bcur, 0, (size_t)(KB_ + 1) * sizeof(int), stream);
    // 2. partition into CAP-strided buckets, plus cls/flag + w1 transpose blocks
    partition_kernel<<<NPBLK + 391 + 128, 256, 0, stream>>>(
        x, w1, src, dst, etype, bcur, ebuf, cls, flag, w1t);
    // 3. per-bucket: folded bscan + rowptr + dense pack + fused layer 0,
    //    plus NTB_ blocks building the pruned-layer needed set
    bfinish_kernel<<<KB_ + NTB_, 512, 0, stream>>>(bcur, ebuf, cls, comp0, V0, loop0, bias0,
                                                   rowptr, pack, cs, hA, flag, cnt, nlist);
    // 4. Layer 1 (full sweep): hA -> hB
    gather_kernel<<<gathBlocks, 256, 0, stream>>>(
        hA, rowptr, pack, comps + 0, Vs + 0, loops + 0, biases + 0, cs, hB, 32);
    // 5. Layer 2 (pruned): hB -> hA
    gatherL_kernel<<<gathBlocks, 256, 0, stream>>>(
        hB, rowptr, pack, comps + 10, Vs + 2048, loops + 1024, biases + 32,
        nlist, cnt, cs, hA, 64);
    // 6. MLP head with fused layer 3 (reads hA), 8 pairs per block
    mlp_kernel<<<B_ / PPB, 256, 0, stream>>>(
        hA, rowptr, pack, comps + 20, Vs + 4096, loops + 2048, biases + 64,
        cs, w1t, b1, w2, b2, out);
}

// Round 15
// 158.762 us; speedup vs baseline: 1.0300x; 1.0300x over previous
//
#include <hip/hip_runtime.h>
#include <hip/hip_fp16.h>

// Problem constants (match reference)
constexpr int N_  = 100000;   // nodes
constexpr int E_  = 1600000;  // edges
constexpr int B_  = 2048;     // pairs
constexpr int NT_ = 2 * B_;   // 4096 target nodes (users+items) read by MLP

constexpr int NPB_SHIFT = 8;                    // 256 nodes per bucket
constexpr int NPB = 1 << NPB_SHIFT;
constexpr int KB_ = (N_ + NPB - 1) / NPB;       // 391 buckets
constexpr int CAP_ = 4608;                      // per-bucket capacity (mean 4096, +8 sigma)
constexpr int PCHUNK = 6250;                    // edges per partition block
constexpr int NPBLK = (E_ + PCHUNK - 1) / PCHUNK; // 256 blocks
constexpr int NTB_ = NT_ / NPB;                 // 16 needed-set blocks (buckets 0..15)
constexpr int HSTR = 21;                        // hist stride (odd -> no bank conflict)

// ================= init: cls + zero(flag,cnt,bcur) + transpose w1 =================
__global__ __launch_bounds__(256) void init_kernel(
    const float* __restrict__ x, const float* __restrict__ w1,
    unsigned char* __restrict__ cls, int* __restrict__ flag,
    int* __restrict__ cnt, int* __restrict__ bcur, float* __restrict__ w1t)
{
    const int b = blockIdx.x, t = threadIdx.x;
    if (b < 391) {
        const int n = b * 256 + t;
        if (n < N_) {
            const float4 v = *(const float4*)(x + n * 4);
            cls[n] = v.y > 0.5f ? 1 : (v.z > 0.5f ? 2 : (v.w > 0.5f ? 3 : 0));
            flag[n] = 0;
        }
        if (b == 0 && t == 0) *cnt = 0;
    } else if (b < 519) {
        const int idx = (b - 391) * 256 + t;   // < 32768
        const int j = idx >> 8, k = idx & 255;
        w1t[k * 128 + j] = w1[idx];
    } else {
        for (int i = t; i < KB_; i += 256) bcur[i] = 0;
    }
}

// ========== partition: edges -> CAP-strided bucket regions (no pre-scan) ==========
// pack word = src(17) | etype(3)<<17 | dloc(8)<<20
__global__ __launch_bounds__(256) void partition_kernel(
    const int* __restrict__ src, const int* __restrict__ dst,
    const int* __restrict__ etype, int* __restrict__ bcur, int* __restrict__ ebuf)
{
    __shared__ int hist[KB_];
    __shared__ int gbase[KB_];
    __shared__ int lcur[KB_];
    const int t = threadIdx.x;
    for (int i = t; i < KB_; i += 256) { hist[i] = 0; lcur[i] = 0; }
    __syncthreads();
    const int e0 = blockIdx.x * PCHUNK;
    const int e1 = min(e0 + PCHUNK, E_);
    for (int i = e0 + t; i < e1; i += 256) atomicAdd(&hist[dst[i] >> NPB_SHIFT], 1);
    __syncthreads();
    for (int i = t; i < KB_; i += 256) if (hist[i]) gbase[i] = atomicAdd(&bcur[i], hist[i]);
    __syncthreads();
    for (int i = e0 + t; i < e1; i += 256) {
        const int d = dst[i];
        const int b = d >> NPB_SHIFT;
        const int lp = atomicAdd(&lcur[b], 1);
        ebuf[(size_t)b * CAP_ + gbase[b] + lp] = src[i] | (etype[i] << 17) | ((d & (NPB - 1)) << 20);
    }
}

// == fused per-bucket: bucket-scan -> hist -> node-scan -> rowptr -> scatter -> L0 ==
// Blocks [0,KB_): CSR + layer 0 for a 256-node bucket. Blocks [KB_,KB_+NTB_):
// needed-set for pruned layer 2 (LDS-buffered appends, 1 global atomic per block).
__global__ __launch_bounds__(512) void bfinish_kernel(
    const int* __restrict__ bcur, const int* __restrict__ ebuf,
    const unsigned char* __restrict__ cls,
    const float* __restrict__ comp0, const float* __restrict__ V0,
    const float* __restrict__ loop0, const float* __restrict__ bias0,
    int* __restrict__ rowptr, int* __restrict__ pack,
    float* __restrict__ cs, __half* __restrict__ hout,
    int* __restrict__ flag, int* __restrict__ cnt_g, int* __restrict__ nlist)
{
    __shared__ int cnt[NPB];                 // scatter cursors
    __shared__ int sh[512];                  // scan workspace (bucket + node scans)
    __shared__ unsigned int hist[NPB * HSTR];// (rel x cls) histogram per node
    __shared__ float sLoop[128], sV0[256], sBias[32], sCmp[10];
    __shared__ int lcnt, gbase_s;
    const int b = blockIdx.x, t = threadIdx.x;
    if (b >= KB_) {
        // ---- needed-set: targets + dedup'd srcs of edges into [0,NT_) ----
        const int tb = b - KB_;              // 0..NTB_-1
        const int s0 = tb * CAP_;
        const int s1 = s0 + bcur[tb];
        const int nbase = tb << NPB_SHIFT;
        int* lbuf = (int*)hist;              // 5376 ints >= 256 + 4608 worst case
        if (t == 0) lcnt = NPB;
        if (t < NPB) lbuf[t] = nbase + t;
        __syncthreads();
        for (int i = s0 + t; i < s1; i += 512) {
            const int s = ebuf[i] & 0x1FFFF;
            if (s >= NT_ && atomicExch(&flag[s], 1) == 0)
                lbuf[atomicAdd(&lcnt, 1)] = s;
        }
        __syncthreads();
        if (t == 0) gbase_s = atomicAdd(cnt_g, lcnt);
        __syncthreads();
        for (int j = t; j < lcnt; j += 512) nlist[gbase_s + j] = lbuf[j];
        return;
    }
    for (int i = t; i < NPB * HSTR; i += 512) hist[i] = 0u;
    if (t < 128) sLoop[t] = loop0[t];
    if (t < 256) sV0[t]   = V0[t];
    if (t < 32)  sBias[t] = bias0[t];
    if (t < 10)  sCmp[t]  = comp0[t];
    // ---- folded bucket scan: exclusive prefix of bcur over KB_ (<512) buckets ----
    sh[t] = (t < KB_) ? bcur[t] : 0;
    __syncthreads();
#pragma unroll
    for (int off = 1; off < 512; off <<= 1) {
        const int u = (t >= off) ? sh[t - off] : 0;
        __syncthreads();
        sh[t] += u;
        __syncthreads();
    }
    const int myCnt = bcur[b];
    const int db = sh[b] - myCnt;            // dense base for this bucket
    const int s0 = b * CAP_;
    const int s1 = s0 + myCnt;
    __syncthreads();                         // sh free for reuse
    for (int i = s0 + t; i < s1; i += 512) {
        const int p = ebuf[i];
        const int et_c = ((p >> 17) & 7) * 4 + cls[p & 0x1FFFF];
        atomicAdd(&hist[(p >> 20) * HSTR + et_c], 1u);
    }
    __syncthreads();
    int v = 0;                               // degree = sum of node's 20 hist entries
    if (t < NPB) {
#pragma unroll
        for (int j = 0; j < 20; ++j) v += (int)hist[t * HSTR + j];
    }
    sh[t] = (t < NPB) ? v : 0;
    __syncthreads();
#pragma unroll
    for (int off = 1; off < NPB; off <<= 1) {
        const int u = (t >= off) ? sh[t - off] : 0;
        __syncthreads();
        sh[t] += u;
        __syncthreads();
    }
    const int node = (b << NPB_SHIFT) + t;
    if (t < NPB) {
        const int rp = db + sh[t] - v;       // dense exclusive prefix + bucket base
        if (node < N_) rowptr[node] = rp;
        cnt[t] = rp;                         // scatter cursor
    }
    if (b == 0 && t == 0) rowptr[N_] = E_;
    __syncthreads();
    for (int i = s0 + t; i < s1; i += 512) {
        const int p = ebuf[i];
        const int pos = atomicAdd(&cnt[p >> 20], 1);
        pack[pos] = p & 0xFFFFF;             // src | etype<<17
    }
    // ---- layer 0 output for this bucket's nodes (hist is stable) ----
    if (t < NPB && node < N_) {
        float A0[4], A1[4];
#pragma unroll
        for (int j = 0; j < 4; ++j) {
            float a0 = 0.f, a1 = 0.f;
#pragma unroll
            for (int r = 0; r < 5; ++r) {
                const float c = (float)hist[t * HSTR + r * 4 + j];
                a0 += c * sCmp[r * 2];
                a1 += c * sCmp[r * 2 + 1];
            }
            A0[j] = a0; A1[j] = a1;
        }
        const int myc = cls[node];
        __half hrow[32];
        const bool wcs = node < NT_;
#pragma unroll 8
        for (int d = 0; d < 32; ++d) {
            float o = sBias[d] + sLoop[myc * 32 + d];
#pragma unroll
            for (int j = 0; j < 4; ++j)
                o += A0[j] * sV0[j * 32 + d] + A1[j] * sV0[128 + j * 32 + d];
            const float r = tanhf(o);
            hrow[d] = __float2half(r);
            if (wcs) cs[node * 128 + d] = r;
        }
        uint4* dst4 = (uint4*)(hout + (size_t)node * 32);
        const uint4* src4 = (const uint4*)hrow;
        dst4[0] = src4[0]; dst4[1] = src4[1]; dst4[2] = src4[2]; dst4[3] = src4[3];
    }
}

// ======================= shared gather body (K = 32) =======================
// 4 lanes per edge; packed fp16 edge accumulation; packed fp16 cross-slot
// reduce; matvec with float4 LDS broadcast reads + coalesced weight reads.
__device__ __forceinline__ void acc_chunk(
    const uint4& v, int pq, bool ok, const __half2* __restrict__ cmp2,
    __half2* h0, __half2* h1)
{
    const int tt = (pq >> 17) & 7;
    const __half2 z = __float2half2_rn(0.f);
    const __half2 c0 = ok ? cmp2[tt * 2]     : z;
    const __half2 c1 = ok ? cmp2[tt * 2 + 1] : z;
    const __half2* hp = (const __half2*)&v;
#pragma unroll
    for (int k = 0; k < 4; ++k) {
        h0[k] = __hfma2(c0, hp[k], h0[k]);
        h1[k] = __hfma2(c1, hp[k], h1[k]);
    }
}

__device__ __forceinline__ float gather_body(
    int n, int lane, int g,
    const __half* __restrict__ hin, const int* __restrict__ rowptr,
    const int* __restrict__ pack, const __half2* __restrict__ cmp2,
    const float* __restrict__ V, const float* __restrict__ loopW,
    const float* __restrict__ bias, float (*hs)[96])
{
    hs[g][lane] = __half2float(hin[n * 32 + lane]);
    const int beg = rowptr[n], end = rowptr[n + 1];
    const int sg = lane >> 2;       // edge slot 0..7
    const int c  = lane & 3;        // dim chunk: dims 8c..8c+7
    const int i0 = beg + sg, i1 = i0 + 8, i2 = i0 + 16, i3 = i0 + 24;
    // 4 independent pack loads
    const int p0 = pack[i0 < end ? i0 : beg];
    const int p1 = pack[i1 < end ? i1 : beg];
    const int p2 = pack[i2 < end ? i2 : beg];
    const int p3 = pack[i3 < end ? i3 : beg];
    // 4 h loads, each dependent only on its own pack word
    const uint4 v0 = *(const uint4*)(hin + (size_t)(p0 & 0x1FFFF) * 32 + c * 8);
    const uint4 v1 = *(const uint4*)(hin + (size_t)(p1 & 0x1FFFF) * 32 + c * 8);
    const uint4 v2 = *(const uint4*)(hin + (size_t)(p2 & 0x1FFFF) * 32 + c * 8);
    const uint4 v3 = *(const uint4*)(hin + (size_t)(p3 & 0x1FFFF) * 32 + c * 8);
    __half2 h0[4], h1[4];
    const __half2 z = __float2half2_rn(0.f);
#pragma unroll
    for (int k = 0; k < 4; ++k) { h0[k] = z; h1[k] = z; }
    acc_chunk(v0, p0, i0 < end, cmp2, h0, h1);
    acc_chunk(v1, p1, i1 < end, cmp2, h0, h1);
    acc_chunk(v2, p2, i2 < end, cmp2, h0, h1);
    acc_chunk(v3, p3, i3 < end, cmp2, h0, h1);
    // rare tail: deg > 32
    for (int e0 = beg + 32; e0 < end; e0 += 8) {
        const int e = e0 + sg;
        const bool ok = e < end;
        const int p = pack[ok ? e : beg];
        const uint4 u = *(const uint4*)(hin + (size_t)(p & 0x1FFFF) * 32 + c * 8);
        acc_chunk(u, p, ok, cmp2, h0, h1);
    }
    // packed fp16 cross-slot reduce (3 rounds over 8 half2 words)
#pragma unroll
    for (int m = 4; m <= 16; m <<= 1) {
#pragma unroll
        for (int k = 0; k < 4; ++k) {
            const int r0 = __shfl_xor(__builtin_bit_cast(int, h0[k]), m, 32);
            const int r1 = __shfl_xor(__builtin_bit_cast(int, h1[k]), m, 32);
            h0[k] = __hadd2(h0[k], __builtin_bit_cast(__half2, r0));
            h1[k] = __hadd2(h1[k], __builtin_bit_cast(__half2, r1));
        }
    }
    if (lane < 4) {
#pragma unroll
        for (int k = 0; k < 4; ++k) {
            const float2 f0 = __half22float2(h0[k]);
            const float2 f1 = __half22float2(h1[k]);
            hs[g][32 + c * 8 + 2 * k]     = f0.x;
            hs[g][32 + c * 8 + 2 * k + 1] = f0.y;
            hs[g][64 + c * 8 + 2 * k]     = f1.x;
            hs[g][64 + c * 8 + 2 * k + 1] = f1.y;
        }
    }
    __builtin_amdgcn_wave_barrier();   // 32-lane group is within one wave64
    // matvec: float4 LDS broadcast reads, weight reads coalesced across lanes
    float o = bias[lane];
#pragma unroll
    for (int k0 = 0; k0 < 32; k0 += 4) {
        const float4 s  = *(const float4*)&hs[g][k0];
        const float4 sa = *(const float4*)&hs[g][32 + k0];
        const float4 sb = *(const float4*)&hs[g][64 + k0];
        o += s.x  * loopW[(k0 + 0) * 32 + lane] + s.y  * loopW[(k0 + 1) * 32 + lane]
           + s.z  * loopW[(k0 + 2) * 32 + lane] + s.w  * loopW[(k0 + 3) * 32 + lane]
           + sa.x * V[(k0 + 0) * 32 + lane]     + sa.y * V[(k0 + 1) * 32 + lane]
           + sa.z * V[(k0 + 2) * 32 + lane]     + sa.w * V[(k0 + 3) * 32 + lane]
           + sb.x * V[1024 + (k0 + 0) * 32 + lane] + sb.y * V[1024 + (k0 + 1) * 32 + lane]
           + sb.z * V[1024 + (k0 + 2) * 32 + lane] + sb.w * V[1024 + (k0 + 3) * 32 + lane];
    }
    return tanhf(o);
}

// Full-sweep gather (layer 1): n = blockIdx*8+g, grid exact
__global__ __launch_bounds__(256) void gather_kernel(
    const __half* __restrict__ hin, const int* __restrict__ rowptr,
    const int* __restrict__ pack, const float* __restrict__ comp,
    const float* __restrict__ V, const float* __restrict__ loopW,
    const float* __restrict__ bias,
    float* __restrict__ cs, __half* __restrict__ hout, int out_off)
{
    __shared__ __align__(16) float hs[8][96];
    __shared__ __half2 cmp2[10];
    const int t = threadIdx.x, lane = t & 31, g = t >> 5;
    if (lane < 10) cmp2[lane] = __float2half2_rn(comp[lane]);  // per-wave benign race
    __builtin_amdgcn_wave_barrier();
    const int n = blockIdx.x * 8 + g;
    const float r = gather_body(n, lane, g, hin, rowptr, pack, cmp2, V, loopW, bias, hs);
    if (n < NT_) cs[n * 128 + out_off + lane] = r;
    hout[n * 32 + lane] = __float2half(r);
}

// Pruned gather over compacted node list (barrier-free -> early exit legal)
__global__ __launch_bounds__(256) void gatherL_kernel(
    const __half* __restrict__ hin, const int* __restrict__ rowptr,
    const int* __restrict__ pack, const float* __restrict__ comp,
    const float* __restrict__ V, const float* __restrict__ loopW,
    const float* __restrict__ bias,
    const int* __restrict__ nlist, const int* __restrict__ cnt,
    float* __restrict__ cs, __half* __restrict__ hout, int out_off)
{
    __shared__ __align__(16) float hs[8][96];
    __shared__ __half2 cmp2[10];
    const int t = threadIdx.x, lane = t & 31, g = t >> 5;
    if (lane < 10) cmp2[lane] = __float2half2_rn(comp[lane]);
    __builtin_amdgcn_wave_barrier();
    const int idx = blockIdx.x * 8 + g;
    if (idx >= *cnt) return;                 // no block barriers below: safe
    const int n = nlist[idx];
    const float r = gather_body(n, lane, g, hin, rowptr, pack, cmp2, V, loopW, bias, hs);
    if (n < NT_) cs[n * 128 + out_off + lane] = r;
    hout[n * 32 + lane] = __float2half(r);
}

// ================= MLP head with fused layer-3 gather (targets only) =============
__global__ __launch_bounds__(128) void mlp_kernel(
    const __half* __restrict__ hin, const int* __restrict__ rowptr,
    const int* __restrict__ pack, const float* __restrict__ comp,
    const float* __restrict__ V, const float* __restrict__ loopW,
    const float* __restrict__ bias,
    const float* __restrict__ cs, const float* __restrict__ w1t,
    const float* __restrict__ b1, const float* __restrict__ w2,
    const float* __restrict__ b2, float* __restrict__ out)
{
    __shared__ __align__(16) float feat[256];
    __shared__ __align__(16) float hs[2][96];
    __shared__ __half2 cmp2[10];
    __shared__ float part[2];
    const int p = blockIdx.x, t = threadIdx.x;
    if (t < 10) cmp2[t] = __float2half2_rn(comp[t]);   // wave 0, before its gather
    if (t < 64) {
        const int g = t >> 5, lane = t & 31;
        const int n = g ? (B_ + p) : p;
        const float r = gather_body(n, lane, g, hin, rowptr, pack, cmp2, V, loopW, bias, hs);
        feat[g * 128 + 96 + lane] = r;
    } else {
        const int i = t - 64;                // 0..63
        for (int j = i; j < 96; j += 64) {
            feat[j]       = cs[p * 128 + j];
            feat[128 + j] = cs[(B_ + p) * 128 + j];
        }
    }
    __syncthreads();
    float acc = b1[t];
#pragma unroll
    for (int k0 = 0; k0 < 256; k0 += 4) {
        const float4 f = *(const float4*)&feat[k0];
        acc += f.x * w1t[(k0 + 0) * 128 + t] + f.y * w1t[(k0 + 1) * 128 + t]
             + f.z * w1t[(k0 + 2) * 128 + t] + f.w * w1t[(k0 + 3) * 128 + t];
    }
    const float hid = acc > 0.f ? acc : 0.f;
    float v = w2[t] * hid;
#pragma unroll
    for (int off = 32; off > 0; off >>= 1) v += __shfl_down(v, off, 64);
    if ((t & 63) == 0) part[t >> 6] = v;
    __syncthreads();
    if (t == 0) out[p] = part[0] + part[1] + b2[0];
}

extern "C" void kernel_launch(void* const* d_in, const int* in_sizes, int n_in,
                              void* d_out, int out_size, void* d_ws, size_t ws_size,
                              hipStream_t stream) {
    const float* x      = (const float*)d_in[0];
    const int*   src    = (const int*)d_in[1];
    const int*   dst    = (const int*)d_in[2];
    const int*   etype  = (const int*)d_in[3];
    const float* V0     = (const float*)d_in[4];
    const float* comp0  = (const float*)d_in[5];
    const float* loop0  = (const float*)d_in[6];
    const float* bias0  = (const float*)d_in[7];
    const float* Vs     = (const float*)d_in[8];    // [3,2,32,32]
    const float* comps  = (const float*)d_in[9];    // [3,5,2]
    const float* loops  = (const float*)d_in[10];   // [3,32,32]
    const float* biases = (const float*)d_in[11];   // [3,32]
    const float* w1     = (const float*)d_in[12];   // [128,256]
    const float* b1     = (const float*)d_in[13];
    const float* w2     = (const float*)d_in[14];   // [1,128]
    const float* b2     = (const float*)d_in[15];
    float* out = (float*)d_out;

    // Workspace layout
    float* ws   = (float*)d_ws;
    float* cs   = ws;                          // NT_*128 floats (target rows only)
    float* w1t  = cs + (size_t)NT_ * 128;      // 256*128 floats
    __half* hA  = (__half*)(w1t + 256 * 128);  // N*32 halves
    __half* hB  = hA + (size_t)N_ * 32;        // N*32 halves
    int* ebuf   = (int*)(hB + (size_t)N_ * 32);   // KB_*CAP_
    int* pack   = ebuf + (size_t)KB_ * CAP_;   // E
    int* rowptr = pack + E_;                   // N+1
    int* flag   = rowptr + N_ + 1;             // N
    int* cnt    = flag + N_;                   // 1
    int* nlist  = cnt + 1;                     // N
    int* bcur   = nlist + N_;                  // KB_
    unsigned char* cls = (unsigned char*)(bcur + KB_);  // N bytes

    const int gathBlocks = N_ / 8;             // 12500 (exact)

    // 1. init: cls + zero flag/cnt/bcur + transpose w1
    init_kernel<<<520, 256, 0, stream>>>(x, w1, cls, flag, cnt, bcur, w1t);
    // 2. partition into CAP-strided buckets (global cursors)
    partition_kernel<<<NPBLK, 256, 0, stream>>>(src, dst, etype, bcur, ebuf);
    // 3. per-bucket: folded bscan + rowptr + dense pack + fused layer 0,
    //    plus NTB_ blocks building the pruned-layer needed set
    bfinish_kernel<<<KB_ + NTB_, 512, 0, stream>>>(bcur, ebuf, cls, comp0, V0, loop0, bias0,
                                                   rowptr, pack, cs, hA, flag, cnt, nlist);
    // 4. Layer 1 (full sweep): hA -> hB
    gather_kernel<<<gathBlocks, 256, 0, stream>>>(
        hA, rowptr, pack, comps + 0, Vs + 0, loops + 0, biases + 0, cs, hB, 32);
    // 5. Layer 2 (pruned): hB -> hA
    gatherL_kernel<<<gathBlocks, 256, 0, stream>>>(
        hB, rowptr, pack, comps + 10, Vs + 2048, loops + 1024, biases + 32,
        nlist, cnt, cs, hA, 64);
    // 6. MLP head with fused layer 3 (reads hA)
    mlp_kernel<<<B_, 128, 0, stream>>>(
        hA, rowptr, pack, comps + 20, Vs + 4096, loops + 2048, biases + 64,
        cs, w1t, b1, w2, b2, out);
}